// Round 18
// baseline (1025.698 us; speedup 1.0000x reference)
//
#include <hip/hip_runtime.h>
#include <hip/hip_bf16.h>
#include <cstdint>

#define NN 50000
#define NNP 50048           // per-pass padded rows (multiple of 64)
#define NEDGE 320000
#define PB (NNP / 64)       // 782 row-blocks per pass
#define EBV 1250            // NEDGE/256
#define SBV 196             // ceil(NN/256)

#define K_F32 0
#define K_BF16 1
#define K_IN 2   // resolve via flags[0]

typedef __attribute__((ext_vector_type(8))) short bf16x8;
typedef __attribute__((ext_vector_type(4))) float f32x4;

// ---------- helpers ----------
__device__ __forceinline__ float bf2f(unsigned short u) {
  return __uint_as_float(((unsigned)u) << 16);
}
__device__ __forceinline__ unsigned short f2bf(float f) {
  unsigned u = __float_as_uint(f);
  unsigned r = ((u >> 16) & 1u) + 0x7FFFu;   // RNE
  return (unsigned short)((u + r) >> 16);
}
__device__ __forceinline__ float load1f(const void* p, size_t i, int isbf) {
  return isbf ? bf2f(((const unsigned short*)p)[i]) : ((const float*)p)[i];
}
__device__ __forceinline__ int maskAt(const void* m, int i, int u8) {
  return u8 ? (int)((const unsigned char*)m)[i] : ((const int*)m)[i];
}
__device__ __forceinline__ void unpack8(uint4 h, float* t) {
  unsigned hw[4] = {h.x, h.y, h.z, h.w};
#pragma unroll
  for (int i = 0; i < 4; ++i) {
    t[2 * i]     = bf2f((unsigned short)(hw[i] & 0xFFFF));
    t[2 * i + 1] = bf2f((unsigned short)(hw[i] >> 16));
  }
}

// ---------- sniff dtypes (flags[0]=floats bf16, [1]=masks u8, [2]=edges i64) ----------
__global__ void sniff_kernel(const void* bg, const void* mask, const void* ei, int* flags) {
  if (threadIdx.x == 0 && blockIdx.x == 0) {
    unsigned w = *(const unsigned*)bg;
    flags[0] = (w == 0x3F800000u) ? 0 : 1;
    const unsigned char* mb = (const unsigned char*)mask;
    int u8 = 0;
    for (int i = 0; i < 1024; ++i)
      if ((i & 3) && mb[i]) { u8 = 1; break; }
    flags[1] = u8;
    const int* ew = (const int*)ei;
    int i64 = 1;
    for (int i = 0; i < 256; ++i)
      if (ew[2 * i + 1] != 0) { i64 = 0; break; }
    flags[2] = i64;
  }
}

__global__ void diag_kernel(void* out, float v) {
  if (threadIdx.x == 0 && blockIdx.x == 0) ((unsigned short*)out)[0] = f2bf(v);
}

// ---------- weight transpose: Wt[n][k] = bf16(W[k][n]) ----------
__global__ void transpose_w(const void* __restrict__ W, const int* __restrict__ flags,
                            unsigned short* __restrict__ Wt, int K, int Ko) {
  int idx = blockIdx.x * 256 + threadIdx.x;
  if (idx >= K * Ko) return;
  int n = idx / K, k = idx - n * K;
  Wt[idx] = f2bf(load1f(W, (size_t)k * Ko + n, flags[0]));
}

// ---------- CSR build (both passes in one launch) ----------
__global__ void csr_hist(const void* __restrict__ e1, const void* __restrict__ e2,
                         const int* __restrict__ flags, int* __restrict__ deg2) {
  int eg = blockIdx.x * 256 + threadIdx.x;        // grid = 2*EBV exact
  int p = eg >= NEDGE ? 1 : 0;
  int e = eg - p * NEDGE;
  const void* eip = p ? e2 : e1;
  int d = flags[2] ? (int)((const long long*)eip)[NEDGE + e] : ((const int*)eip)[NEDGE + e];
  atomicAdd(deg2 + p * 50016 + d, 1);
}

__global__ void scan1(const int* __restrict__ deg2, int* __restrict__ rowptr2,
                      int* __restrict__ bsum2) {
  __shared__ int sm[256];
  int t = threadIdx.x;
  int p = blockIdx.x >= SBV ? 1 : 0;
  int b = blockIdx.x - p * SBV;
  int i = b * 256 + t;
  int v = (i < NN) ? deg2[p * 50016 + i] : 0;
  sm[t] = v; __syncthreads();
  for (int o = 1; o < 256; o <<= 1) {
    int y = (t >= o) ? sm[t - o] : 0;
    __syncthreads();
    sm[t] += y;
    __syncthreads();
  }
  if (i < NN) rowptr2[p * 50016 + i] = sm[t] - v;
  if (t == 255) bsum2[p * 256 + b] = sm[255];
}

__global__ void scan2(int* __restrict__ bsum2) {
  __shared__ int sm[256];
  int t = threadIdx.x;
  int* arr = bsum2 + blockIdx.x * 256;            // grid = 2
  int v = (t < SBV) ? arr[t] : 0;
  sm[t] = v; __syncthreads();
  for (int o = 1; o < 256; o <<= 1) {
    int y = (t >= o) ? sm[t - o] : 0;
    __syncthreads();
    sm[t] += y;
    __syncthreads();
  }
  arr[t] = sm[t] - v;
}

__global__ void scan3(int* __restrict__ rowptr2, const int* __restrict__ bsum2,
                      int* __restrict__ cursor2) {
  int p = blockIdx.x >= SBV ? 1 : 0;
  int b = blockIdx.x - p * SBV;
  int i = b * 256 + threadIdx.x;
  if (i < NN) {
    int r = rowptr2[p * 50016 + i] + bsum2[p * 256 + b];
    rowptr2[p * 50016 + i] = r;
    cursor2[p * 50016 + i] = r;
  } else if (i == NN) {
    rowptr2[p * 50016 + NN] = NEDGE;
  }
}

__global__ void csr_fill(const void* __restrict__ e1, const void* __restrict__ e2,
                         const int* __restrict__ flags,
                         int* __restrict__ cursor2, int* __restrict__ adj2) {
  int eg = blockIdx.x * 256 + threadIdx.x;        // grid = 2*EBV
  int p = eg >= NEDGE ? 1 : 0;
  int e = eg - p * NEDGE;
  const void* eip = p ? e2 : e1;
  int s, d;
  if (flags[2]) {
    s = (int)((const long long*)eip)[e];
    d = (int)((const long long*)eip)[NEDGE + e];
  } else {
    s = ((const int*)eip)[e];
    d = ((const int*)eip)[NEDGE + e];
  }
  int pos = atomicAdd(cursor2 + p * 50016 + d, 1);
  adj2[p * NEDGE + pos] = s;
}

// ---------- fused gather, dual-pass: H[p*NNP+v] = T(feat) + sum_nbr T(feat) ----------
template<int F, bool MASKED, bool BN, bool ISBF, bool SHARED>
__device__ __forceinline__ void gf_body(const void* __restrict__ feat,
                                        const void* __restrict__ maskp,
                                        const int* __restrict__ adj,
                                        int s0, int s1, int v, size_t pbase,
                                        int lane, int mu8,
                                        const float* __restrict__ sc,
                                        const float* __restrict__ sh,
                                        float* __restrict__ a) {
  constexpr int VEC = F / 64;
  auto ld = [&](int r, float* t) {
    size_t frow = SHARED ? (size_t)r : (pbase + r);
    size_t gb = frow * F + lane * VEC;
    if (ISBF) {
      if (VEC == 4) {
        ushort4 h = *(const ushort4*)((const unsigned short*)feat + gb);
        t[0] = bf2f(h.x); t[1] = bf2f(h.y); t[2] = bf2f(h.z); t[3] = bf2f(h.w);
      } else {
        ushort2 h = *(const ushort2*)((const unsigned short*)feat + gb);
        t[0] = bf2f(h.x); t[1] = bf2f(h.y);
      }
    } else {
      if (VEC == 4) {
        float4 h = *(const float4*)((const float*)feat + gb);
        t[0] = h.x; t[1] = h.y; t[2] = h.z; t[3] = h.w;
      } else {
        float2 h = *(const float2*)((const float*)feat + gb);
        t[0] = h.x; t[1] = h.y;
      }
    }
    if (BN) {
#pragma unroll
      for (int i = 0; i < VEC; ++i) t[i] = fmaxf(0.f, t[i] * sc[i] + sh[i]);
    }
  };
  {
    float t[VEC];
    ld(v, t);
    float m = (MASKED && maskAt(maskp, v, mu8)) ? 0.f : 1.f;
#pragma unroll
    for (int i = 0; i < VEC; ++i) a[i] = m * t[i];
  }
  int e = s0;
  for (; e + 4 <= s1; e += 4) {
    int n0 = adj[e], n1 = adj[e + 1], n2 = adj[e + 2], n3 = adj[e + 3];
    float m0 = 1.f, m1 = 1.f, m2 = 1.f, m3 = 1.f;
    if (MASKED) {
      m0 = maskAt(maskp, n0, mu8) ? 0.f : 1.f;
      m1 = maskAt(maskp, n1, mu8) ? 0.f : 1.f;
      m2 = maskAt(maskp, n2, mu8) ? 0.f : 1.f;
      m3 = maskAt(maskp, n3, mu8) ? 0.f : 1.f;
    }
    float t0[VEC], t1[VEC], t2[VEC], t3[VEC];
    ld(n0, t0); ld(n1, t1); ld(n2, t2); ld(n3, t3);
#pragma unroll
    for (int i = 0; i < VEC; ++i)
      a[i] += m0 * t0[i] + m1 * t1[i] + m2 * t2[i] + m3 * t3[i];
  }
  for (; e < s1; ++e) {
    int s = adj[e];
    if (MASKED && maskAt(maskp, s, mu8)) continue;
    float t[VEC];
    ld(s, t);
#pragma unroll
    for (int i = 0; i < VEC; ++i) a[i] += t[i];
  }
}

template<int F, bool MASKED, bool BN, bool SHARED>
__launch_bounds__(256)
__global__ void gather_fused(const void* __restrict__ feat, int kind,
                             const void* __restrict__ mk1, const void* __restrict__ mk2,
                             const int* __restrict__ rowptr2, const int* __restrict__ adj2,
                             const float* __restrict__ ss,
                             const int* __restrict__ flags,
                             unsigned short* __restrict__ outH) {
  constexpr int VEC = F / 64;
  int w = (blockIdx.x * 256 + threadIdx.x) >> 6;   // [0, 2*NN), grid exact
  int p = w >= NN ? 1 : 0;
  int v = w - p * NN;
  int lane = threadIdx.x & 63;
  int mu8 = flags[1];
  const void* mk = p ? mk2 : mk1;
  const int* rp_ = rowptr2 + p * 50016;
  const int* aj = adj2 + p * NEDGE;
  const float* ssp = ss + p * 2 * F;
  size_t pbase = (size_t)p * NNP;
  float sc[VEC], sh[VEC];
  if (BN) {
#pragma unroll
    for (int i = 0; i < VEC; ++i) {
      sc[i] = ssp[lane * VEC + i];
      sh[i] = ssp[F + lane * VEC + i];
    }
  }
  float a[VEC];
  int s0 = rp_[v], s1 = rp_[v + 1];
  int fbf = (kind == K_IN) ? flags[0] : kind;
  if (fbf) gf_body<F, MASKED, BN, true, SHARED>(feat, mk, aj, s0, s1, v, pbase, lane, mu8, sc, sh, a);
  else     gf_body<F, MASKED, BN, false, SHARED>(feat, mk, aj, s0, s1, v, pbase, lane, mu8, sc, sh, a);
  size_t ob = (pbase + v) * F + lane * VEC;
  if (VEC == 4) {
    ushort4 o; o.x = f2bf(a[0]); o.y = f2bf(a[1]); o.z = f2bf(a[2]); o.w = f2bf(a[3]);
    *(ushort4*)(outH + ob) = o;
  } else {
    ushort2 o; o.x = f2bf(a[0]); o.y = f2bf(a[1]);
    *(ushort2*)(outH + ob) = o;
  }
}

// ---------- MFMA GEMM, dual-pass, BK=64, depth-3 per-substep B rotation ----------
// blockIdx.x in [0, 2*PB); pass = x >= PB. 64 rows x (KO/SPLIT) cols per block.
// LDS A double-buffered 64x64 chunks (stride 72 shorts); A raw 1 chunk ahead;
// B register-buffered breg[3][NTW], substep (32k) granularity, 2 substeps ahead.
template<int K, int KO, int SPLIT, bool BNF>
__launch_bounds__(256)
__global__ void gemm_mfma(const unsigned short* __restrict__ A,     // [2*NNP][K] bf16
                          const float* __restrict__ ss,
                          const unsigned short* __restrict__ Wt,    // [KO][K] bf16
                          unsigned short* __restrict__ Cout,        // [2*NNP][KO]
                          float* __restrict__ stats) {
  constexpr int NTW = KO / (SPLIT * 64);
  constexpr int NC = K / 64;
  constexpr int NS = 2 * NC;                      // 32k substeps
  __shared__ __align__(16) unsigned short As[2][64 * 72];
  const int tid = threadIdx.x;
  const int pass = (blockIdx.x >= PB) ? 1 : 0;
  const int row0 = blockIdx.x * 64;
  const int colBase = blockIdx.y * (KO / SPLIT);
  const int srow = tid >> 2;            // 0..63
  const int sk = (tid & 3) * 16;        // 0,16,32,48
  const int grow = row0 + srow;
  const bool valid = (grow - pass * NNP) < NN;
  const int wv = tid >> 6, lane = tid & 63;
  const int l15 = lane & 15, quad = lane >> 4;
  const int n0 = colBase + wv * (KO / SPLIT / 4);
  const float* ssp = BNF ? (ss + pass * 2 * K) : ss;
  float* statsp = stats + pass * 1024;
  f32x4 zero = {0.f, 0.f, 0.f, 0.f};
  f32x4 acc[4][NTW];
#pragma unroll
  for (int m = 0; m < 4; ++m)
#pragma unroll
    for (int nt = 0; nt < NTW; ++nt) acc[m][nt] = zero;

  ushort4 pbh[2][4];           // [set][quarter] — A raw (16 elems), set = chunk & 1
  bf16x8 breg[3][NTW];         // B fragments, rotated by substep % 3

  auto issue_A = [&](int kt, int set) {
    if (!valid) return;
    const ushort4* P = (const ushort4*)(A + (size_t)grow * K + kt + sk);
#pragma unroll
    for (int i = 0; i < 4; ++i) pbh[set][i] = P[i];
  };
  auto issue_B32 = [&](int kt, int buf) {
#pragma unroll
    for (int nt = 0; nt < NTW; ++nt)
      breg[buf][nt] = *(const bf16x8*)(Wt + (size_t)(n0 + nt * 16 + l15) * K + kt + quad * 8);
  };
  auto transform_store = [&](int kt, int set, unsigned short* buf) {
    float v[16];
    if (valid) {
#pragma unroll
      for (int i = 0; i < 4; ++i) {
        v[4 * i] = bf2f(pbh[set][i].x); v[4 * i + 1] = bf2f(pbh[set][i].y);
        v[4 * i + 2] = bf2f(pbh[set][i].z); v[4 * i + 3] = bf2f(pbh[set][i].w);
      }
      if (BNF) {
        int j = kt + sk;
#pragma unroll
        for (int i = 0; i < 16; ++i)
          v[i] = fmaxf(0.f, v[i] * ssp[j + i] + ssp[K + j + i]);
      }
    } else {
#pragma unroll
      for (int i = 0; i < 16; ++i) v[i] = 0.f;
    }
    unsigned short* dst = buf + srow * 72 + sk;
#pragma unroll
    for (int i = 0; i < 4; ++i) {
      ushort4 o;
      o.x = f2bf(v[4 * i]); o.y = f2bf(v[4 * i + 1]);
      o.z = f2bf(v[4 * i + 2]); o.w = f2bf(v[4 * i + 3]);
      *(ushort4*)(dst + 4 * i) = o;
    }
  };

  // prologue: chunk0 staged; A raw chunk1 in flight; B substeps 0,1 in flight
  issue_A(0, 0);
  transform_store(0, 0, As[0]);
  if (NC > 1) issue_A(64, 1);
  issue_B32(0, 0);
  if (NS > 1) issue_B32(32, 1);
  __syncthreads();

#pragma unroll
  for (int i = 0; i < NC; ++i) {
    const int kt = i * 64;
    if (i + 1 < NC) transform_store(kt + 64, (i + 1) & 1, As[(i + 1) & 1]);
    if (i + 2 < NC) issue_A(kt + 128, i & 1);
#pragma unroll
    for (int ks = 0; ks < 2; ++ks) {
      const int gs = 2 * i + ks;                      // global substep (compile-time)
      if (gs + 2 < NS) {
        const int ns = gs + 2;
        issue_B32((ns >> 1) * 64 + (ns & 1) * 32, ns % 3);
      }
      bf16x8 afr[4];
#pragma unroll
      for (int m = 0; m < 4; ++m)
        afr[m] = *(const bf16x8*)(As[i & 1] + (m * 16 + l15) * 72 + ks * 32 + quad * 8);
#pragma unroll
      for (int nt = 0; nt < NTW; ++nt)
#pragma unroll
        for (int m = 0; m < 4; ++m)
          acc[m][nt] = __builtin_amdgcn_mfma_f32_16x16x32_bf16(afr[m], breg[gs % 3][nt], acc[m][nt], 0, 0, 0);
    }
    __syncthreads();
  }

#pragma unroll
  for (int m = 0; m < 4; ++m)
#pragma unroll
    for (int r = 0; r < 4; ++r) {
      int gr = row0 + m * 16 + quad * 4 + r;
      if (gr - pass * NNP < NN) {
        size_t ob = (size_t)gr * KO + n0 + l15;
#pragma unroll
        for (int nt = 0; nt < NTW; ++nt)
          Cout[ob + nt * 16] = f2bf(acc[m][nt][r]);
      }
    }

#pragma unroll
  for (int nt = 0; nt < NTW; ++nt) {
    float s = 0.f, q = 0.f;
#pragma unroll
    for (int m = 0; m < 4; ++m)
#pragma unroll
      for (int r = 0; r < 4; ++r) {
        float vv = acc[m][nt][r];
        s += vv; q += vv * vv;
      }
    s += __shfl_xor(s, 16); s += __shfl_xor(s, 32);
    q += __shfl_xor(q, 16); q += __shfl_xor(q, 32);
    if (quad == 0) {
      int col = n0 + nt * 16 + l15;
      atomicAdd(statsp + col, s);
      atomicAdd(statsp + KO + col, q);
    }
  }
}

// ---------- BN finalize, both passes (grid.y = pass) ----------
__global__ void bn_finalize(const float* __restrict__ sums, const void* __restrict__ g,
                            const void* __restrict__ b, const int* __restrict__ flags,
                            float* __restrict__ ss, int Ko) {
  int c = blockIdx.x * blockDim.x + threadIdx.x;
  int p = blockIdx.y;
  if (c < Ko) {
    const float invN = 1.f / (float)NN;
    float mu = sums[p * 1024 + c] * invN;
    float var = sums[p * 1024 + Ko + c] * invN - mu * mu;
    float sc = load1f(g, c, flags[0]) * rsqrtf(var + 1e-5f);
    ss[p * 2 * Ko + c] = sc;
    ss[p * 2 * Ko + Ko + c] = load1f(b, c, flags[0]) - mu * sc;
  }
}

// ---------- combined loss: both recon losses + contrastive, one kernel ----------
__launch_bounds__(256)
__global__ void loss_all(const unsigned short* __restrict__ U2, const float* __restrict__ ss,
                         const void* __restrict__ xp,
                         const void* __restrict__ mk1, const void* __restrict__ mk2,
                         const int* __restrict__ flags, float* __restrict__ accb) {
  __shared__ float r1S[4], r1C[4], r2S[4], r2C[4], rL[4];
  const int lane = threadIdx.x & 63;
  const int wv = threadIdx.x >> 6;
  const int g = lane >> 4, li = lane & 15;
  const int v = blockIdx.x * 16 + wv * 4 + g;
  const int fbf = flags[0], mu8 = flags[1];
  const int j0 = li * 8;
  size_t o1 = (size_t)v * 128 + j0;
  size_t o2 = ((size_t)NNP + v) * 128 + j0;

  float a1[8], a2[8], xv[8];
  unpack8(*(const uint4*)(U2 + o1), a1);
  unpack8(*(const uint4*)(U2 + o2), a2);
#pragma unroll
  for (int i = 0; i < 8; ++i) {
    a1[i] = fmaxf(0.f, a1[i] * ss[j0 + i]       + ss[128 + j0 + i]);
    a2[i] = fmaxf(0.f, a2[i] * ss[256 + j0 + i] + ss[384 + j0 + i]);
    a1[i] = bf2f(f2bf(a1[i]));
    a2[i] = bf2f(f2bf(a2[i]));
  }
  if (fbf) {
    unpack8(*(const uint4*)((const unsigned short*)xp + o1), xv);
  } else {
    const float* xf = (const float*)xp + o1;
    float4 h0 = *(const float4*)xf;
    float4 h1 = *(const float4*)(xf + 4);
    xv[0] = h0.x; xv[1] = h0.y; xv[2] = h0.z; xv[3] = h0.w;
    xv[4] = h1.x; xv[5] = h1.y; xv[6] = h1.z; xv[7] = h1.w;
  }
  float d1 = 0.f, d2 = 0.f, dc = 0.f, n1 = 0.f, n2 = 0.f, nx = 0.f;
#pragma unroll
  for (int i = 0; i < 8; ++i) {
    d1 += a1[i] * xv[i];
    d2 += a2[i] * xv[i];
    dc += a2[i] * a1[i];
    n1 += a1[i] * a1[i];
    n2 += a2[i] * a2[i];
    nx += xv[i] * xv[i];
  }
#pragma unroll
  for (int off = 1; off < 16; off <<= 1) {
    d1 += __shfl_xor(d1, off);
    d2 += __shfl_xor(d2, off);
    dc += __shfl_xor(dc, off);
    n1 += __shfl_xor(n1, off);
    n2 += __shfl_xor(n2, off);
    nx += __shfl_xor(nx, off);
  }
  float s1 = fmaxf(sqrtf(n1), 1e-12f), s2 = fmaxf(sqrtf(n2), 1e-12f);
  float sx = fmaxf(sqrtf(nx), 1e-12f);
  float cs1 = d1 / (s1 * sx), cs2 = d2 / (s2 * sx), csc = dc / (s2 * s1);
  float l1 = 0.f, c1 = 0.f, l2 = 0.f, c2 = 0.f;
  if (maskAt(mk1, v, mu8)) { l1 = 1.f - cs1; c1 = 1.f; }
  if (maskAt(mk2, v, mu8)) { l2 = 1.f - cs2; c2 = 1.f; }
  float cl = 1.f - csc;
  l1 += __shfl_xor(l1, 16); l1 += __shfl_xor(l1, 32);
  c1 += __shfl_xor(c1, 16); c1 += __shfl_xor(c1, 32);
  l2 += __shfl_xor(l2, 16); l2 += __shfl_xor(l2, 32);
  c2 += __shfl_xor(c2, 16); c2 += __shfl_xor(c2, 32);
  cl += __shfl_xor(cl, 16); cl += __shfl_xor(cl, 32);
  if (lane == 0) { r1S[wv] = l1; r1C[wv] = c1; r2S[wv] = l2; r2C[wv] = c2; rL[wv] = cl; }
  __syncthreads();
  if (threadIdx.x == 0) {
    int bin = (blockIdx.x & 63) * 16;
    atomicAdd(&accb[bin],        r1S[0] + r1S[1] + r1S[2] + r1S[3]);
    atomicAdd(&accb[1024 + bin], r1C[0] + r1C[1] + r1C[2] + r1C[3]);
    atomicAdd(&accb[2048 + bin], r2S[0] + r2S[1] + r2S[2] + r2S[3]);
    atomicAdd(&accb[3072 + bin], r2C[0] + r2C[1] + r2C[2] + r2C[3]);
    atomicAdd(&accb[4096 + bin], rL[0] + rL[1] + rL[2] + rL[3]);
  }
}

// ---------- final: reduce 64-bin accumulators (stride-16) ----------
__global__ void final_kernel(const float* __restrict__ acc, void* __restrict__ out,
                             const int* __restrict__ flags) {
  int lane = threadIdx.x & 63;
  float v0 = acc[lane * 16], v1 = acc[1024 + lane * 16], v2 = acc[2048 + lane * 16];
  float v3 = acc[3072 + lane * 16], v4 = acc[4096 + lane * 16];
#pragma unroll
  for (int off = 32; off > 0; off >>= 1) {
    v0 += __shfl_xor(v0, off);
    v1 += __shfl_xor(v1, off);
    v2 += __shfl_xor(v2, off);
    v3 += __shfl_xor(v3, off);
    v4 += __shfl_xor(v4, off);
  }
  if (threadIdx.x == 0 && blockIdx.x == 0) {
    float v = v0 / v1 + v2 / v3 + 0.1f * (v4 / (float)NN);
    if (flags[0]) ((unsigned short*)out)[0] = f2bf(v);
    else          ((float*)out)[0] = v;
  }
}

extern "C" void kernel_launch(void* const* d_in, const int* in_sizes, int n_in,
                              void* d_out, int out_size, void* d_ws, size_t ws_size,
                              hipStream_t stream) {
  const void* x   = d_in[0];
  const void* ei1 = d_in[1];
  const void* ei2 = d_in[2];
  const void* m1  = d_in[3];
  const void* m2  = d_in[4];
  const void* e0_w1 = d_in[6],  *e0_w2 = d_in[7],  *e0_bg = d_in[8],  *e0_bb = d_in[9];
  const void* e0_ng = d_in[10], *e0_nb = d_in[11];
  const void* e1_w1 = d_in[12], *e1_w2 = d_in[13], *e1_bg = d_in[14], *e1_bb = d_in[15];
  const void* e1_ng = d_in[16], *e1_nb = d_in[17];
  const void* dw1 = d_in[18], *dw2 = d_in[19], *dbg = d_in[20], *dbb = d_in[21];
  const void* dng = d_in[22], *dnb = d_in[23];

  // ---- workspace layout (dual-pass buffers, rows 2*NNP) ----
  char* p = (char*)d_ws;
  const size_t NR = 2 * (size_t)NNP;
  const size_t OFS_T      = 0;                                  // bf16 NR*512
  const size_t OFS_H      = OFS_T      + NR * 512 * 2;          // bf16 NR*256
  const size_t OFS_U      = OFS_H      + NR * 256 * 2;          // bf16 NR*256
  const size_t OFS_WT     = OFS_U      + NR * 256 * 2;          // bf16 655360
  const size_t OFS_ROWPTR = OFS_WT     + 655360 * 2;            // int 2*50016
  const size_t OFS_CURSOR = OFS_ROWPTR + 2 * 50016 * 4;         // int 2*50016
  const size_t OFS_ADJ    = OFS_CURSOR + 2 * 50016 * 4;         // int 2*NEDGE
  const size_t OFS_BSUM   = OFS_ADJ    + 2 * (size_t)NEDGE * 4; // int 512
  const size_t OFS_STATS  = OFS_BSUM   + 512 * 4;               // f 12*1024
  const size_t OFS_SS     = OFS_STATS  + 12 * 1024 * 4;         // f 2048
  const size_t OFS_ACC    = OFS_SS     + 2048 * 4;              // f 5120
  const size_t OFS_FLAGS  = OFS_ACC    + 5120 * 4;              // i 4
  const size_t NEED       = OFS_FLAGS + 16;

  if (ws_size < NEED) {
    diag_kernel<<<1, 64, 0, stream>>>(d_out, (float)(ws_size >> 20));
    return;
  }

  unsigned short* T   = (unsigned short*)(p + OFS_T);
  unsigned short* H   = (unsigned short*)(p + OFS_H);
  unsigned short* U   = (unsigned short*)(p + OFS_U);
  unsigned short* WT  = (unsigned short*)(p + OFS_WT);
  int* rowptr2 = (int*)(p + OFS_ROWPTR);
  int* cursor2 = (int*)(p + OFS_CURSOR);
  int* adj2    = (int*)(p + OFS_ADJ);
  int* bsum2   = (int*)(p + OFS_BSUM);
  float* stats = (float*)(p + OFS_STATS);
  float* ss    = (float*)(p + OFS_SS);
  float* acc   = (float*)(p + OFS_ACC);
  int*   flags = (int*)(p + OFS_FLAGS);

  const int GB2 = 2 * PB;                    // 1564 row-blocks (both passes)
  const int WB2 = 2 * NN / 4;                // 25000 gather blocks
  const int LB  = NN / 16;                   // 3125 loss blocks
  const dim3 gS2(GB2, 2), gS1(GB2, 1);
  const dim3 bn512((512 + 255) / 256, 2), bn256(1, 2), bn128(1, 2);

  hipMemsetAsync(stats, 0, (12 * 1024 + 2048 + 5120) * 4 + 16, stream);  // stats+ss+acc+flags
  hipMemsetAsync(cursor2, 0, 2 * 50016 * 4, stream);
  sniff_kernel<<<1, 64, 0, stream>>>(e0_bg, m1, ei1, flags);

  // weight transposes (once; bf16)
  transpose_w<<<(128 * 512 + 255) / 256, 256, 0, stream>>>(e0_w1, flags, WT + 0,      128, 512);
  transpose_w<<<(512 * 256 + 255) / 256, 256, 0, stream>>>(e0_w2, flags, WT + 65536,  512, 256);
  transpose_w<<<(256 * 512 + 255) / 256, 256, 0, stream>>>(e1_w1, flags, WT + 196608, 256, 512);
  transpose_w<<<(512 * 256 + 255) / 256, 256, 0, stream>>>(e1_w2, flags, WT + 327680, 512, 256);
  transpose_w<<<(256 * 512 + 255) / 256, 256, 0, stream>>>(dw1,   flags, WT + 458752, 256, 512);
  transpose_w<<<(512 * 128 + 255) / 256, 256, 0, stream>>>(dw2,   flags, WT + 589824, 512, 128);

  // ---- CSR build, both passes ----
  csr_hist<<<2 * EBV, 256, 0, stream>>>(ei1, ei2, flags, cursor2);
  scan1<<<2 * SBV, 256, 0, stream>>>(cursor2, rowptr2, bsum2);
  scan2<<<2, 256, 0, stream>>>(bsum2);
  scan3<<<2 * SBV, 256, 0, stream>>>(rowptr2, bsum2, cursor2);
  csr_fill<<<2 * EBV, 256, 0, stream>>>(ei1, ei2, flags, cursor2, adj2);

  // ---- encoder L0 (128 -> 512 -> 256), both passes ----
  gather_fused<128, true, false, true><<<WB2, 256, 0, stream>>>(
      x, K_IN, m1, m2, rowptr2, adj2, nullptr, flags, H);
  gemm_mfma<128, 512, 2, false><<<gS2, 256, 0, stream>>>(H, nullptr, WT + 0, T, stats);
  bn_finalize<<<bn512, 256, 0, stream>>>(stats, e0_bg, e0_bb, flags, ss, 512);
  gemm_mfma<512, 256, 1, true><<<gS1, 256, 0, stream>>>(T, ss, WT + 65536, U, stats + 2048);
  bn_finalize<<<bn256, 256, 0, stream>>>(stats + 2048, e0_ng, e0_nb, flags, ss, 256);

  // ---- encoder L1 (256 -> 512 -> 256): bnrelu fused into gather ----
  gather_fused<256, false, true, false><<<WB2, 256, 0, stream>>>(
      U, K_BF16, nullptr, nullptr, rowptr2, adj2, ss, flags, H);
  gemm_mfma<256, 512, 2, false><<<gS2, 256, 0, stream>>>(H, nullptr, WT + 196608, T, stats + 4096);
  bn_finalize<<<bn512, 256, 0, stream>>>(stats + 4096, e1_bg, e1_bb, flags, ss, 512);
  gemm_mfma<512, 256, 1, true><<<gS1, 256, 0, stream>>>(T, ss, WT + 327680, U, stats + 6144);
  bn_finalize<<<bn256, 256, 0, stream>>>(stats + 6144, e1_ng, e1_nb, flags, ss, 256);

  // ---- decoder (256 -> 512 -> 128): mask + bnrelu fused into gather ----
  gather_fused<256, true, true, false><<<WB2, 256, 0, stream>>>(
      U, K_BF16, m1, m2, rowptr2, adj2, ss, flags, H);
  gemm_mfma<256, 512, 2, false><<<gS2, 256, 0, stream>>>(H, nullptr, WT + 458752, T, stats + 8192);
  bn_finalize<<<bn512, 256, 0, stream>>>(stats + 8192, dbg, dbb, flags, ss, 512);
  gemm_mfma<512, 128, 1, true><<<gS1, 256, 0, stream>>>(T, ss, WT + 589824, U, stats + 10240);
  bn_finalize<<<bn128, 256, 0, stream>>>(stats + 10240, dng, dnb, flags, ss, 128);

  // ---- losses (both recon + contrastive) ----
  loss_all<<<LB, 256, 0, stream>>>(U, ss, x, m1, m2, flags, acc);
  final_kernel<<<1, 64, 0, stream>>>(acc, d_out, flags);
}

// Round 19
// 994.010 us; speedup vs baseline: 1.0319x; 1.0319x over previous
//
#include <hip/hip_runtime.h>
#include <hip/hip_bf16.h>
#include <cstdint>

#define NN 50000
#define NNP 50048           // per-pass padded rows (multiple of 64)
#define NEDGE 320000
#define PB (NNP / 64)       // 782 row-blocks per pass
#define EBV 1250            // NEDGE/256
#define SBV 196             // ceil(NN/256)

#define K_F32 0
#define K_BF16 1
#define K_IN 2   // resolve via flags[0]

typedef __attribute__((ext_vector_type(8))) short bf16x8;
typedef __attribute__((ext_vector_type(4))) float f32x4;

// ---------- helpers ----------
__device__ __forceinline__ float bf2f(unsigned short u) {
  return __uint_as_float(((unsigned)u) << 16);
}
__device__ __forceinline__ unsigned short f2bf(float f) {
  unsigned u = __float_as_uint(f);
  unsigned r = ((u >> 16) & 1u) + 0x7FFFu;   // RNE
  return (unsigned short)((u + r) >> 16);
}
__device__ __forceinline__ float load1f(const void* p, size_t i, int isbf) {
  return isbf ? bf2f(((const unsigned short*)p)[i]) : ((const float*)p)[i];
}
__device__ __forceinline__ int maskAt(const void* m, int i, int u8) {
  return u8 ? (int)((const unsigned char*)m)[i] : ((const int*)m)[i];
}
__device__ __forceinline__ void unpack8(uint4 h, float* t) {
  unsigned hw[4] = {h.x, h.y, h.z, h.w};
#pragma unroll
  for (int i = 0; i < 4; ++i) {
    t[2 * i]     = bf2f((unsigned short)(hw[i] & 0xFFFF));
    t[2 * i + 1] = bf2f((unsigned short)(hw[i] >> 16));
  }
}

// ---------- sniff dtypes (flags[0]=floats bf16, [1]=masks u8, [2]=edges i64) ----------
__global__ void sniff_kernel(const void* bg, const void* mask, const void* ei, int* flags) {
  if (threadIdx.x == 0 && blockIdx.x == 0) {
    unsigned w = *(const unsigned*)bg;
    flags[0] = (w == 0x3F800000u) ? 0 : 1;
    const unsigned char* mb = (const unsigned char*)mask;
    int u8 = 0;
    for (int i = 0; i < 1024; ++i)
      if ((i & 3) && mb[i]) { u8 = 1; break; }
    flags[1] = u8;
    const int* ew = (const int*)ei;
    int i64 = 1;
    for (int i = 0; i < 256; ++i)
      if (ew[2 * i + 1] != 0) { i64 = 0; break; }
    flags[2] = i64;
  }
}

__global__ void diag_kernel(void* out, float v) {
  if (threadIdx.x == 0 && blockIdx.x == 0) ((unsigned short*)out)[0] = f2bf(v);
}

// ---------- weight transpose: Wt[n][k] = bf16(W[k][n]) ----------
__global__ void transpose_w(const void* __restrict__ W, const int* __restrict__ flags,
                            unsigned short* __restrict__ Wt, int K, int Ko) {
  int idx = blockIdx.x * 256 + threadIdx.x;
  if (idx >= K * Ko) return;
  int n = idx / K, k = idx - n * K;
  Wt[idx] = f2bf(load1f(W, (size_t)k * Ko + n, flags[0]));
}

// ---------- CSR build (both passes in one launch) ----------
__global__ void csr_hist(const void* __restrict__ e1, const void* __restrict__ e2,
                         const int* __restrict__ flags, int* __restrict__ deg2) {
  int eg = blockIdx.x * 256 + threadIdx.x;        // grid = 2*EBV exact
  int p = eg >= NEDGE ? 1 : 0;
  int e = eg - p * NEDGE;
  const void* eip = p ? e2 : e1;
  int d = flags[2] ? (int)((const long long*)eip)[NEDGE + e] : ((const int*)eip)[NEDGE + e];
  atomicAdd(deg2 + p * 50016 + d, 1);
}

__global__ void scan1(const int* __restrict__ deg2, int* __restrict__ rowptr2,
                      int* __restrict__ bsum2) {
  __shared__ int sm[256];
  int t = threadIdx.x;
  int p = blockIdx.x >= SBV ? 1 : 0;
  int b = blockIdx.x - p * SBV;
  int i = b * 256 + t;
  int v = (i < NN) ? deg2[p * 50016 + i] : 0;
  sm[t] = v; __syncthreads();
  for (int o = 1; o < 256; o <<= 1) {
    int y = (t >= o) ? sm[t - o] : 0;
    __syncthreads();
    sm[t] += y;
    __syncthreads();
  }
  if (i < NN) rowptr2[p * 50016 + i] = sm[t] - v;
  if (t == 255) bsum2[p * 256 + b] = sm[255];
}

__global__ void scan2(int* __restrict__ bsum2) {
  __shared__ int sm[256];
  int t = threadIdx.x;
  int* arr = bsum2 + blockIdx.x * 256;            // grid = 2
  int v = (t < SBV) ? arr[t] : 0;
  sm[t] = v; __syncthreads();
  for (int o = 1; o < 256; o <<= 1) {
    int y = (t >= o) ? sm[t - o] : 0;
    __syncthreads();
    sm[t] += y;
    __syncthreads();
  }
  arr[t] = sm[t] - v;
}

__global__ void scan3(int* __restrict__ rowptr2, const int* __restrict__ bsum2,
                      int* __restrict__ cursor2) {
  int p = blockIdx.x >= SBV ? 1 : 0;
  int b = blockIdx.x - p * SBV;
  int i = b * 256 + threadIdx.x;
  if (i < NN) {
    int r = rowptr2[p * 50016 + i] + bsum2[p * 256 + b];
    rowptr2[p * 50016 + i] = r;
    cursor2[p * 50016 + i] = r;
  } else if (i == NN) {
    rowptr2[p * 50016 + NN] = NEDGE;
  }
}

__global__ void csr_fill(const void* __restrict__ e1, const void* __restrict__ e2,
                         const int* __restrict__ flags,
                         int* __restrict__ cursor2, int* __restrict__ adj2) {
  int eg = blockIdx.x * 256 + threadIdx.x;        // grid = 2*EBV
  int p = eg >= NEDGE ? 1 : 0;
  int e = eg - p * NEDGE;
  const void* eip = p ? e2 : e1;
  int s, d;
  if (flags[2]) {
    s = (int)((const long long*)eip)[e];
    d = (int)((const long long*)eip)[NEDGE + e];
  } else {
    s = ((const int*)eip)[e];
    d = ((const int*)eip)[NEDGE + e];
  }
  int pos = atomicAdd(cursor2 + p * 50016 + d, 1);
  adj2[p * NEDGE + pos] = s;
}

// ---------- fused gather, dual-pass: H[p*NNP+v] = T(feat) + sum_nbr T(feat) ----------
template<int F, bool MASKED, bool BN, bool ISBF, bool SHARED>
__device__ __forceinline__ void gf_body(const void* __restrict__ feat,
                                        const void* __restrict__ maskp,
                                        const int* __restrict__ adj,
                                        int s0, int s1, int v, size_t pbase,
                                        int lane, int mu8,
                                        const float* __restrict__ sc,
                                        const float* __restrict__ sh,
                                        float* __restrict__ a) {
  constexpr int VEC = F / 64;
  auto ld = [&](int r, float* t) {
    size_t frow = SHARED ? (size_t)r : (pbase + r);
    size_t gb = frow * F + lane * VEC;
    if (ISBF) {
      if (VEC == 4) {
        ushort4 h = *(const ushort4*)((const unsigned short*)feat + gb);
        t[0] = bf2f(h.x); t[1] = bf2f(h.y); t[2] = bf2f(h.z); t[3] = bf2f(h.w);
      } else {
        ushort2 h = *(const ushort2*)((const unsigned short*)feat + gb);
        t[0] = bf2f(h.x); t[1] = bf2f(h.y);
      }
    } else {
      if (VEC == 4) {
        float4 h = *(const float4*)((const float*)feat + gb);
        t[0] = h.x; t[1] = h.y; t[2] = h.z; t[3] = h.w;
      } else {
        float2 h = *(const float2*)((const float*)feat + gb);
        t[0] = h.x; t[1] = h.y;
      }
    }
    if (BN) {
#pragma unroll
      for (int i = 0; i < VEC; ++i) t[i] = fmaxf(0.f, t[i] * sc[i] + sh[i]);
    }
  };
  {
    float t[VEC];
    ld(v, t);
    float m = (MASKED && maskAt(maskp, v, mu8)) ? 0.f : 1.f;
#pragma unroll
    for (int i = 0; i < VEC; ++i) a[i] = m * t[i];
  }
  int e = s0;
  for (; e + 4 <= s1; e += 4) {
    int n0 = adj[e], n1 = adj[e + 1], n2 = adj[e + 2], n3 = adj[e + 3];
    float m0 = 1.f, m1 = 1.f, m2 = 1.f, m3 = 1.f;
    if (MASKED) {
      m0 = maskAt(maskp, n0, mu8) ? 0.f : 1.f;
      m1 = maskAt(maskp, n1, mu8) ? 0.f : 1.f;
      m2 = maskAt(maskp, n2, mu8) ? 0.f : 1.f;
      m3 = maskAt(maskp, n3, mu8) ? 0.f : 1.f;
    }
    float t0[VEC], t1[VEC], t2[VEC], t3[VEC];
    ld(n0, t0); ld(n1, t1); ld(n2, t2); ld(n3, t3);
#pragma unroll
    for (int i = 0; i < VEC; ++i)
      a[i] += m0 * t0[i] + m1 * t1[i] + m2 * t2[i] + m3 * t3[i];
  }
  for (; e < s1; ++e) {
    int s = adj[e];
    if (MASKED && maskAt(maskp, s, mu8)) continue;
    float t[VEC];
    ld(s, t);
#pragma unroll
    for (int i = 0; i < VEC; ++i) a[i] += t[i];
  }
}

template<int F, bool MASKED, bool BN, bool SHARED>
__launch_bounds__(256)
__global__ void gather_fused(const void* __restrict__ feat, int kind,
                             const void* __restrict__ mk1, const void* __restrict__ mk2,
                             const int* __restrict__ rowptr2, const int* __restrict__ adj2,
                             const float* __restrict__ ss,
                             const int* __restrict__ flags,
                             unsigned short* __restrict__ outH) {
  constexpr int VEC = F / 64;
  int w = (blockIdx.x * 256 + threadIdx.x) >> 6;   // [0, 2*NN), grid exact
  int p = w >= NN ? 1 : 0;
  int v = w - p * NN;
  int lane = threadIdx.x & 63;
  int mu8 = flags[1];
  const void* mk = p ? mk2 : mk1;
  const int* rp_ = rowptr2 + p * 50016;
  const int* aj = adj2 + p * NEDGE;
  const float* ssp = ss + p * 2 * F;
  size_t pbase = (size_t)p * NNP;
  float sc[VEC], sh[VEC];
  if (BN) {
#pragma unroll
    for (int i = 0; i < VEC; ++i) {
      sc[i] = ssp[lane * VEC + i];
      sh[i] = ssp[F + lane * VEC + i];
    }
  }
  float a[VEC];
  int s0 = rp_[v], s1 = rp_[v + 1];
  int fbf = (kind == K_IN) ? flags[0] : kind;
  if (fbf) gf_body<F, MASKED, BN, true, SHARED>(feat, mk, aj, s0, s1, v, pbase, lane, mu8, sc, sh, a);
  else     gf_body<F, MASKED, BN, false, SHARED>(feat, mk, aj, s0, s1, v, pbase, lane, mu8, sc, sh, a);
  size_t ob = (pbase + v) * F + lane * VEC;
  if (VEC == 4) {
    ushort4 o; o.x = f2bf(a[0]); o.y = f2bf(a[1]); o.z = f2bf(a[2]); o.w = f2bf(a[3]);
    *(ushort4*)(outH + ob) = o;
  } else {
    ushort2 o; o.x = f2bf(a[0]); o.y = f2bf(a[1]);
    *(ushort2*)(outH + ob) = o;
  }
}

// ---------- MFMA GEMM, dual-pass, BK=64 chunks (round-17 best config) ----------
// blockIdx.x in [0, 2*PB); pass = x >= PB. 64 rows x (KO/SPLIT) cols per block.
// LDS A double-buffered 64x64 chunks (stride 72 shorts, 16B-aligned rows);
// A raw 1 chunk ahead (2 sets); B register-buffered 2-deep x 2 substeps.
template<int K, int KO, int SPLIT, bool BNF>
__launch_bounds__(256)
__global__ void gemm_mfma(const unsigned short* __restrict__ A,     // [2*NNP][K] bf16
                          const float* __restrict__ ss,
                          const unsigned short* __restrict__ Wt,    // [KO][K] bf16
                          unsigned short* __restrict__ Cout,        // [2*NNP][KO]
                          float* __restrict__ stats) {
  constexpr int NTW = KO / (SPLIT * 64);
  constexpr int NC = K / 64;
  __shared__ __align__(16) unsigned short As[2][64 * 72];
  const int tid = threadIdx.x;
  const int pass = (blockIdx.x >= PB) ? 1 : 0;
  const int row0 = blockIdx.x * 64;
  const int colBase = blockIdx.y * (KO / SPLIT);
  const int srow = tid >> 2;            // 0..63
  const int sk = (tid & 3) * 16;        // 0,16,32,48
  const int grow = row0 + srow;
  const bool valid = (grow - pass * NNP) < NN;
  const int wv = tid >> 6, lane = tid & 63;
  const int l15 = lane & 15, quad = lane >> 4;
  const int n0 = colBase + wv * (KO / SPLIT / 4);
  const float* ssp = BNF ? (ss + pass * 2 * K) : ss;
  float* statsp = stats + pass * 1024;
  f32x4 zero = {0.f, 0.f, 0.f, 0.f};
  f32x4 acc[4][NTW];
#pragma unroll
  for (int m = 0; m < 4; ++m)
#pragma unroll
    for (int nt = 0; nt < NTW; ++nt) acc[m][nt] = zero;

  ushort4 pbh[2][4];           // [set][quarter] — A raw (16 elems), set = chunk & 1
  bf16x8 breg[2][2][NTW];      // [buf][substep][nt]

  auto issue_A = [&](int kt, int set) {
    if (!valid) return;
    const ushort4* P = (const ushort4*)(A + (size_t)grow * K + kt + sk);
#pragma unroll
    for (int i = 0; i < 4; ++i) pbh[set][i] = P[i];
  };
  auto issue_B = [&](int kt, int buf) {
#pragma unroll
    for (int ks = 0; ks < 2; ++ks)
#pragma unroll
      for (int nt = 0; nt < NTW; ++nt)
        breg[buf][ks][nt] =
            *(const bf16x8*)(Wt + (size_t)(n0 + nt * 16 + l15) * K + kt + ks * 32 + quad * 8);
  };
  auto transform_store = [&](int kt, int set, unsigned short* buf) {
    float v[16];
    if (valid) {
#pragma unroll
      for (int i = 0; i < 4; ++i) {
        v[4 * i] = bf2f(pbh[set][i].x); v[4 * i + 1] = bf2f(pbh[set][i].y);
        v[4 * i + 2] = bf2f(pbh[set][i].z); v[4 * i + 3] = bf2f(pbh[set][i].w);
      }
      if (BNF) {
        int j = kt + sk;
#pragma unroll
        for (int i = 0; i < 16; ++i)
          v[i] = fmaxf(0.f, v[i] * ssp[j + i] + ssp[K + j + i]);
      }
    } else {
#pragma unroll
      for (int i = 0; i < 16; ++i) v[i] = 0.f;
    }
    unsigned short* dst = buf + srow * 72 + sk;
#pragma unroll
    for (int i = 0; i < 4; ++i) {
      ushort4 o;
      o.x = f2bf(v[4 * i]); o.y = f2bf(v[4 * i + 1]);
      o.z = f2bf(v[4 * i + 2]); o.w = f2bf(v[4 * i + 3]);
      *(ushort4*)(dst + 4 * i) = o;
    }
  };

  // prologue: chunk0 staged; A raw chunk1 in flight; B chunks 0,1 in flight
  issue_A(0, 0);
  transform_store(0, 0, As[0]);
  if (NC > 1) issue_A(64, 1);
  issue_B(0, 0);
  if (NC > 1) issue_B(64, 1);
  __syncthreads();

#pragma unroll
  for (int i = 0; i < NC; ++i) {
    const int kt = i * 64;
    if (i + 1 < NC) transform_store(kt + 64, (i + 1) & 1, As[(i + 1) & 1]);
    if (i + 2 < NC) issue_A(kt + 128, i & 1);
    if (i + 2 < NC) issue_B(kt + 128, i & 1);
#pragma unroll
    for (int ks = 0; ks < 2; ++ks) {
      bf16x8 afr[4];
#pragma unroll
      for (int m = 0; m < 4; ++m)
        afr[m] = *(const bf16x8*)(As[i & 1] + (m * 16 + l15) * 72 + ks * 32 + quad * 8);
#pragma unroll
      for (int nt = 0; nt < NTW; ++nt)
#pragma unroll
        for (int m = 0; m < 4; ++m)
          acc[m][nt] = __builtin_amdgcn_mfma_f32_16x16x32_bf16(afr[m], breg[i & 1][ks][nt], acc[m][nt], 0, 0, 0);
    }
    __syncthreads();
  }

#pragma unroll
  for (int m = 0; m < 4; ++m)
#pragma unroll
    for (int r = 0; r < 4; ++r) {
      int gr = row0 + m * 16 + quad * 4 + r;
      if (gr - pass * NNP < NN) {
        size_t ob = (size_t)gr * KO + n0 + l15;
#pragma unroll
        for (int nt = 0; nt < NTW; ++nt)
          Cout[ob + nt * 16] = f2bf(acc[m][nt][r]);
      }
    }

#pragma unroll
  for (int nt = 0; nt < NTW; ++nt) {
    float s = 0.f, q = 0.f;
#pragma unroll
    for (int m = 0; m < 4; ++m)
#pragma unroll
      for (int r = 0; r < 4; ++r) {
        float vv = acc[m][nt][r];
        s += vv; q += vv * vv;
      }
    s += __shfl_xor(s, 16); s += __shfl_xor(s, 32);
    q += __shfl_xor(q, 16); q += __shfl_xor(q, 32);
    if (quad == 0) {
      int col = n0 + nt * 16 + l15;
      atomicAdd(statsp + col, s);
      atomicAdd(statsp + KO + col, q);
    }
  }
}

// ---------- BN finalize, both passes (grid.y = pass) ----------
__global__ void bn_finalize(const float* __restrict__ sums, const void* __restrict__ g,
                            const void* __restrict__ b, const int* __restrict__ flags,
                            float* __restrict__ ss, int Ko) {
  int c = blockIdx.x * blockDim.x + threadIdx.x;
  int p = blockIdx.y;
  if (c < Ko) {
    const float invN = 1.f / (float)NN;
    float mu = sums[p * 1024 + c] * invN;
    float var = sums[p * 1024 + Ko + c] * invN - mu * mu;
    float sc = load1f(g, c, flags[0]) * rsqrtf(var + 1e-5f);
    ss[p * 2 * Ko + c] = sc;
    ss[p * 2 * Ko + Ko + c] = load1f(b, c, flags[0]) - mu * sc;
  }
}

// ---------- combined loss: both recon losses + contrastive, one kernel ----------
__launch_bounds__(256)
__global__ void loss_all(const unsigned short* __restrict__ U2, const float* __restrict__ ss,
                         const void* __restrict__ xp,
                         const void* __restrict__ mk1, const void* __restrict__ mk2,
                         const int* __restrict__ flags, float* __restrict__ accb) {
  __shared__ float r1S[4], r1C[4], r2S[4], r2C[4], rL[4];
  const int lane = threadIdx.x & 63;
  const int wv = threadIdx.x >> 6;
  const int g = lane >> 4, li = lane & 15;
  const int v = blockIdx.x * 16 + wv * 4 + g;
  const int fbf = flags[0], mu8 = flags[1];
  const int j0 = li * 8;
  size_t o1 = (size_t)v * 128 + j0;
  size_t o2 = ((size_t)NNP + v) * 128 + j0;

  float a1[8], a2[8], xv[8];
  unpack8(*(const uint4*)(U2 + o1), a1);
  unpack8(*(const uint4*)(U2 + o2), a2);
#pragma unroll
  for (int i = 0; i < 8; ++i) {
    a1[i] = fmaxf(0.f, a1[i] * ss[j0 + i]       + ss[128 + j0 + i]);
    a2[i] = fmaxf(0.f, a2[i] * ss[256 + j0 + i] + ss[384 + j0 + i]);
    a1[i] = bf2f(f2bf(a1[i]));
    a2[i] = bf2f(f2bf(a2[i]));
  }
  if (fbf) {
    unpack8(*(const uint4*)((const unsigned short*)xp + o1), xv);
  } else {
    const float* xf = (const float*)xp + o1;
    float4 h0 = *(const float4*)xf;
    float4 h1 = *(const float4*)(xf + 4);
    xv[0] = h0.x; xv[1] = h0.y; xv[2] = h0.z; xv[3] = h0.w;
    xv[4] = h1.x; xv[5] = h1.y; xv[6] = h1.z; xv[7] = h1.w;
  }
  float d1 = 0.f, d2 = 0.f, dc = 0.f, n1 = 0.f, n2 = 0.f, nx = 0.f;
#pragma unroll
  for (int i = 0; i < 8; ++i) {
    d1 += a1[i] * xv[i];
    d2 += a2[i] * xv[i];
    dc += a2[i] * a1[i];
    n1 += a1[i] * a1[i];
    n2 += a2[i] * a2[i];
    nx += xv[i] * xv[i];
  }
#pragma unroll
  for (int off = 1; off < 16; off <<= 1) {
    d1 += __shfl_xor(d1, off);
    d2 += __shfl_xor(d2, off);
    dc += __shfl_xor(dc, off);
    n1 += __shfl_xor(n1, off);
    n2 += __shfl_xor(n2, off);
    nx += __shfl_xor(nx, off);
  }
  float s1 = fmaxf(sqrtf(n1), 1e-12f), s2 = fmaxf(sqrtf(n2), 1e-12f);
  float sx = fmaxf(sqrtf(nx), 1e-12f);
  float cs1 = d1 / (s1 * sx), cs2 = d2 / (s2 * sx), csc = dc / (s2 * s1);
  float l1 = 0.f, c1 = 0.f, l2 = 0.f, c2 = 0.f;
  if (maskAt(mk1, v, mu8)) { l1 = 1.f - cs1; c1 = 1.f; }
  if (maskAt(mk2, v, mu8)) { l2 = 1.f - cs2; c2 = 1.f; }
  float cl = 1.f - csc;
  l1 += __shfl_xor(l1, 16); l1 += __shfl_xor(l1, 32);
  c1 += __shfl_xor(c1, 16); c1 += __shfl_xor(c1, 32);
  l2 += __shfl_xor(l2, 16); l2 += __shfl_xor(l2, 32);
  c2 += __shfl_xor(c2, 16); c2 += __shfl_xor(c2, 32);
  cl += __shfl_xor(cl, 16); cl += __shfl_xor(cl, 32);
  if (lane == 0) { r1S[wv] = l1; r1C[wv] = c1; r2S[wv] = l2; r2C[wv] = c2; rL[wv] = cl; }
  __syncthreads();
  if (threadIdx.x == 0) {
    int bin = (blockIdx.x & 63) * 16;
    atomicAdd(&accb[bin],        r1S[0] + r1S[1] + r1S[2] + r1S[3]);
    atomicAdd(&accb[1024 + bin], r1C[0] + r1C[1] + r1C[2] + r1C[3]);
    atomicAdd(&accb[2048 + bin], r2S[0] + r2S[1] + r2S[2] + r2S[3]);
    atomicAdd(&accb[3072 + bin], r2C[0] + r2C[1] + r2C[2] + r2C[3]);
    atomicAdd(&accb[4096 + bin], rL[0] + rL[1] + rL[2] + rL[3]);
  }
}

// ---------- final: reduce 64-bin accumulators (stride-16) ----------
__global__ void final_kernel(const float* __restrict__ acc, void* __restrict__ out,
                             const int* __restrict__ flags) {
  int lane = threadIdx.x & 63;
  float v0 = acc[lane * 16], v1 = acc[1024 + lane * 16], v2 = acc[2048 + lane * 16];
  float v3 = acc[3072 + lane * 16], v4 = acc[4096 + lane * 16];
#pragma unroll
  for (int off = 32; off > 0; off >>= 1) {
    v0 += __shfl_xor(v0, off);
    v1 += __shfl_xor(v1, off);
    v2 += __shfl_xor(v2, off);
    v3 += __shfl_xor(v3, off);
    v4 += __shfl_xor(v4, off);
  }
  if (threadIdx.x == 0 && blockIdx.x == 0) {
    float v = v0 / v1 + v2 / v3 + 0.1f * (v4 / (float)NN);
    if (flags[0]) ((unsigned short*)out)[0] = f2bf(v);
    else          ((float*)out)[0] = v;
  }
}

extern "C" void kernel_launch(void* const* d_in, const int* in_sizes, int n_in,
                              void* d_out, int out_size, void* d_ws, size_t ws_size,
                              hipStream_t stream) {
  const void* x   = d_in[0];
  const void* ei1 = d_in[1];
  const void* ei2 = d_in[2];
  const void* m1  = d_in[3];
  const void* m2  = d_in[4];
  const void* e0_w1 = d_in[6],  *e0_w2 = d_in[7],  *e0_bg = d_in[8],  *e0_bb = d_in[9];
  const void* e0_ng = d_in[10], *e0_nb = d_in[11];
  const void* e1_w1 = d_in[12], *e1_w2 = d_in[13], *e1_bg = d_in[14], *e1_bb = d_in[15];
  const void* e1_ng = d_in[16], *e1_nb = d_in[17];
  const void* dw1 = d_in[18], *dw2 = d_in[19], *dbg = d_in[20], *dbb = d_in[21];
  const void* dng = d_in[22], *dnb = d_in[23];

  // ---- workspace layout (dual-pass buffers, rows 2*NNP) ----
  char* p = (char*)d_ws;
  const size_t NR = 2 * (size_t)NNP;
  const size_t OFS_T      = 0;                                  // bf16 NR*512
  const size_t OFS_H      = OFS_T      + NR * 512 * 2;          // bf16 NR*256
  const size_t OFS_U      = OFS_H      + NR * 256 * 2;          // bf16 NR*256
  const size_t OFS_WT     = OFS_U      + NR * 256 * 2;          // bf16 655360
  const size_t OFS_ROWPTR = OFS_WT     + 655360 * 2;            // int 2*50016
  const size_t OFS_CURSOR = OFS_ROWPTR + 2 * 50016 * 4;         // int 2*50016
  const size_t OFS_ADJ    = OFS_CURSOR + 2 * 50016 * 4;         // int 2*NEDGE
  const size_t OFS_BSUM   = OFS_ADJ    + 2 * (size_t)NEDGE * 4; // int 512
  const size_t OFS_STATS  = OFS_BSUM   + 512 * 4;               // f 12*1024
  const size_t OFS_SS     = OFS_STATS  + 12 * 1024 * 4;         // f 2048
  const size_t OFS_ACC    = OFS_SS     + 2048 * 4;              // f 5120
  const size_t OFS_FLAGS  = OFS_ACC    + 5120 * 4;              // i 4
  const size_t NEED       = OFS_FLAGS + 16;

  if (ws_size < NEED) {
    diag_kernel<<<1, 64, 0, stream>>>(d_out, (float)(ws_size >> 20));
    return;
  }

  unsigned short* T   = (unsigned short*)(p + OFS_T);
  unsigned short* H   = (unsigned short*)(p + OFS_H);
  unsigned short* U   = (unsigned short*)(p + OFS_U);
  unsigned short* WT  = (unsigned short*)(p + OFS_WT);
  int* rowptr2 = (int*)(p + OFS_ROWPTR);
  int* cursor2 = (int*)(p + OFS_CURSOR);
  int* adj2    = (int*)(p + OFS_ADJ);
  int* bsum2   = (int*)(p + OFS_BSUM);
  float* stats = (float*)(p + OFS_STATS);
  float* ss    = (float*)(p + OFS_SS);
  float* acc   = (float*)(p + OFS_ACC);
  int*   flags = (int*)(p + OFS_FLAGS);

  const int GB2 = 2 * PB;                    // 1564 row-blocks (both passes)
  const int WB2 = 2 * NN / 4;                // 25000 gather blocks
  const int LB  = NN / 16;                   // 3125 loss blocks
  const dim3 gS2(GB2, 2), gS1(GB2, 1);
  const dim3 bn512((512 + 255) / 256, 2), bn256(1, 2), bn128(1, 2);

  hipMemsetAsync(stats, 0, (12 * 1024 + 2048 + 5120) * 4 + 16, stream);  // stats+ss+acc+flags
  hipMemsetAsync(cursor2, 0, 2 * 50016 * 4, stream);
  sniff_kernel<<<1, 64, 0, stream>>>(e0_bg, m1, ei1, flags);

  // weight transposes (once; bf16)
  transpose_w<<<(128 * 512 + 255) / 256, 256, 0, stream>>>(e0_w1, flags, WT + 0,      128, 512);
  transpose_w<<<(512 * 256 + 255) / 256, 256, 0, stream>>>(e0_w2, flags, WT + 65536,  512, 256);
  transpose_w<<<(256 * 512 + 255) / 256, 256, 0, stream>>>(e1_w1, flags, WT + 196608, 256, 512);
  transpose_w<<<(512 * 256 + 255) / 256, 256, 0, stream>>>(e1_w2, flags, WT + 327680, 512, 256);
  transpose_w<<<(256 * 512 + 255) / 256, 256, 0, stream>>>(dw1,   flags, WT + 458752, 256, 512);
  transpose_w<<<(512 * 128 + 255) / 256, 256, 0, stream>>>(dw2,   flags, WT + 589824, 512, 128);

  // ---- CSR build, both passes ----
  csr_hist<<<2 * EBV, 256, 0, stream>>>(ei1, ei2, flags, cursor2);
  scan1<<<2 * SBV, 256, 0, stream>>>(cursor2, rowptr2, bsum2);
  scan2<<<2, 256, 0, stream>>>(bsum2);
  scan3<<<2 * SBV, 256, 0, stream>>>(rowptr2, bsum2, cursor2);
  csr_fill<<<2 * EBV, 256, 0, stream>>>(ei1, ei2, flags, cursor2, adj2);

  // ---- encoder L0 (128 -> 512 -> 256), both passes ----
  gather_fused<128, true, false, true><<<WB2, 256, 0, stream>>>(
      x, K_IN, m1, m2, rowptr2, adj2, nullptr, flags, H);
  gemm_mfma<128, 512, 2, false><<<gS2, 256, 0, stream>>>(H, nullptr, WT + 0, T, stats);
  bn_finalize<<<bn512, 256, 0, stream>>>(stats, e0_bg, e0_bb, flags, ss, 512);
  gemm_mfma<512, 256, 1, true><<<gS1, 256, 0, stream>>>(T, ss, WT + 65536, U, stats + 2048);
  bn_finalize<<<bn256, 256, 0, stream>>>(stats + 2048, e0_ng, e0_nb, flags, ss, 256);

  // ---- encoder L1 (256 -> 512 -> 256): bnrelu fused into gather ----
  gather_fused<256, false, true, false><<<WB2, 256, 0, stream>>>(
      U, K_BF16, nullptr, nullptr, rowptr2, adj2, ss, flags, H);
  gemm_mfma<256, 512, 2, false><<<gS2, 256, 0, stream>>>(H, nullptr, WT + 196608, T, stats + 4096);
  bn_finalize<<<bn512, 256, 0, stream>>>(stats + 4096, e1_bg, e1_bb, flags, ss, 512);
  gemm_mfma<512, 256, 1, true><<<gS1, 256, 0, stream>>>(T, ss, WT + 327680, U, stats + 6144);
  bn_finalize<<<bn256, 256, 0, stream>>>(stats + 6144, e1_ng, e1_nb, flags, ss, 256);

  // ---- decoder (256 -> 512 -> 128): mask + bnrelu fused into gather ----
  gather_fused<256, true, true, false><<<WB2, 256, 0, stream>>>(
      U, K_BF16, m1, m2, rowptr2, adj2, ss, flags, H);
  gemm_mfma<256, 512, 2, false><<<gS2, 256, 0, stream>>>(H, nullptr, WT + 458752, T, stats + 8192);
  bn_finalize<<<bn512, 256, 0, stream>>>(stats + 8192, dbg, dbb, flags, ss, 512);
  gemm_mfma<512, 128, 1, true><<<gS1, 256, 0, stream>>>(T, ss, WT + 589824, U, stats + 10240);
  bn_finalize<<<bn128, 256, 0, stream>>>(stats + 10240, dng, dnb, flags, ss, 128);

  // ---- losses (both recon + contrastive) ----
  loss_all<<<LB, 256, 0, stream>>>(U, ss, x, m1, m2, flags, acc);
  final_kernel<<<1, 64, 0, stream>>>(acc, d_out, flags);
}